// Round 1
// baseline (573.366 us; speedup 1.0000x reference)
//
#include <hip/hip_runtime.h>

typedef unsigned short u16;
typedef unsigned int u32;
typedef __bf16 bf16x8 __attribute__((ext_vector_type(8)));
typedef float f32x4 __attribute__((ext_vector_type(4)));
typedef u16 u16x4v __attribute__((ext_vector_type(4)));
typedef u16 u16x8v __attribute__((ext_vector_type(8)));

#define MFMA16(a, b, c) __builtin_amdgcn_mfma_f32_16x16x32_bf16((a), (b), (c), 0, 0, 0)

__device__ __forceinline__ u16 f2bf(float f) {
  union { float f; u32 u; } v; v.f = f;
  u32 r = v.u + 0x7fffu + ((v.u >> 16) & 1u);
  return (u16)(r >> 16);
}

__device__ __forceinline__ bf16x8 ld_bf8(const u16* p) {
  u16x8v t = *(const u16x8v*)p;
  return __builtin_bit_cast(bf16x8, t);
}

// ---------------- cast fp32 -> bf16 (vectorized) ----------------
__global__ __launch_bounds__(256) void cast_bf16(const float* __restrict__ in,
                                                 u16* __restrict__ out, int n4) {
  int idx = blockIdx.x * 256 + threadIdx.x;
  int stride = gridDim.x * 256;
  for (int i = idx; i < n4; i += stride) {
    float4 v = ((const float4*)in)[i];
    u16x4v o = {f2bf(v.x), f2bf(v.y), f2bf(v.z), f2bf(v.w)};
    *(u16x4v*)(out + (size_t)i * 4) = o;
  }
}

// ---------------- cast+transpose fp32 W[R][C] -> bf16 WT[C][R] ----------------
__global__ __launch_bounds__(256) void cast_transpose(const float* __restrict__ W,
                                                      u16* __restrict__ WT, int R, int C) {
  __shared__ float t[32][33];
  int bx = blockIdx.x * 32, by = blockIdx.y * 32;
  int tx = threadIdx.x, ty = threadIdx.y;  // (32,8)
#pragma unroll
  for (int i = 0; i < 4; i++)
    t[ty + i * 8][tx] = W[(size_t)(by + ty + i * 8) * C + bx + tx];
  __syncthreads();
#pragma unroll
  for (int i = 0; i < 4; i++)
    WT[(size_t)(bx + ty + i * 8) * R + by + tx] = f2bf(t[tx][ty + i * 8]);
}

// ---------------- transpose bf16 V[R][C] -> VT[C][R] ----------------
__global__ __launch_bounds__(256) void transpose_bf16(const u16* __restrict__ V,
                                                      u16* __restrict__ VT, int R, int C) {
  __shared__ u16 t[32][33];
  int bx = blockIdx.x * 32, by = blockIdx.y * 32;
  int tx = threadIdx.x, ty = threadIdx.y;
#pragma unroll
  for (int i = 0; i < 4; i++)
    t[ty + i * 8][tx] = V[(size_t)(by + ty + i * 8) * C + bx + tx];
  __syncthreads();
#pragma unroll
  for (int i = 0; i < 4; i++)
    VT[(size_t)(bx + ty + i * 8) * R + by + tx] = t[tx][ty + i * 8];
}

// ---------------- GEMM: C[M][N] = alpha*(A[M][K] @ BT[N][K]^T + bias[N]) ----------------
// 128x128 tile, BK=64, 256 threads = 4 waves in 2x2, each wave 64x64 (4x4 MFMA frags)
template <bool OUT_F32>
__global__ __launch_bounds__(256) void gemm_bt(const u16* __restrict__ A,
                                               const u16* __restrict__ BT,
                                               const float* __restrict__ bias,
                                               void* __restrict__ Cout,
                                               int M, int N, int K, float alpha) {
  __shared__ u16 As[128][64];
  __shared__ u16 Bs[128][64];
  const int tid = threadIdx.x;
  const int lane = tid & 63, wid = tid >> 6;
  const int wm = wid >> 1, wn = wid & 1;
  const int bm0 = blockIdx.y * 128, bn0 = blockIdx.x * 128;
  const int lr = lane & 15, lg = lane >> 4;

  f32x4 acc[4][4] = {};

  for (int k0 = 0; k0 < K; k0 += 64) {
    __syncthreads();
#pragma unroll
    for (int i = 0; i < 4; i++) {
      int c = tid + i * 256;          // 0..1023
      int row = c >> 3, k8 = c & 7;   // 128 rows x 8 chunks of 8 bf16
      u16x8v va = *(const u16x8v*)(A + (size_t)(bm0 + row) * K + k0 + k8 * 8);
      *(u16x8v*)&As[row][k8 * 8] = va;
      u16x8v vb = *(const u16x8v*)(BT + (size_t)(bn0 + row) * K + k0 + k8 * 8);
      *(u16x8v*)&Bs[row][k8 * 8] = vb;
    }
    __syncthreads();
#pragma unroll
    for (int kk = 0; kk < 2; kk++) {
      bf16x8 af[4], bfr[4];
#pragma unroll
      for (int i = 0; i < 4; i++)
        af[i] = ld_bf8(&As[wm * 64 + i * 16 + lr][kk * 32 + lg * 8]);
#pragma unroll
      for (int j = 0; j < 4; j++)
        bfr[j] = ld_bf8(&Bs[wn * 64 + j * 16 + lr][kk * 32 + lg * 8]);
#pragma unroll
      for (int i = 0; i < 4; i++)
#pragma unroll
        for (int j = 0; j < 4; j++)
          acc[i][j] = MFMA16(af[i], bfr[j], acc[i][j]);
    }
  }

  // epilogue
#pragma unroll
  for (int i = 0; i < 4; i++) {
#pragma unroll
    for (int j = 0; j < 4; j++) {
      int col = bn0 + wn * 64 + j * 16 + lr;
      float bv = bias[col];
#pragma unroll
      for (int r = 0; r < 4; r++) {
        int row = bm0 + wm * 64 + i * 16 + lg * 4 + r;
        float v = alpha * (acc[i][j][r] + bv);
        if (OUT_F32)
          ((float*)Cout)[(size_t)row * N + col] = v;
        else
          ((u16*)Cout)[(size_t)row * N + col] = f2bf(v);
      }
    }
  }
}

// ---------------- Flash attention ----------------
// Q,K: [4096][2048] bf16 (row = b*2048+s, col = h*128+d), Q pre-scaled by 1/sqrt(D)
// VT: [2048][4096] bf16 (row = h*128+d, col = b*2048+s)
// Ctx out: [4096][2048] bf16
__global__ __launch_bounds__(256) void attn_kernel(const u16* __restrict__ Q,
                                                   const u16* __restrict__ K,
                                                   const u16* __restrict__ VT,
                                                   u16* __restrict__ Ctx) {
  const int HID = 2048, SEQ = 2048, MROWS = 4096;
  __shared__ u16 Ks[64][136];   // [kv][d] padded
  __shared__ u16 Vs[128][72];   // [d][kv] padded
  __shared__ u16 Ps[4][16][72]; // per-wave P [q][kv] padded

  const int bh = blockIdx.y;
  const int b = bh >> 4, h = bh & 15;
  const int q0 = blockIdx.x * 64;
  const int tid = threadIdx.x;
  const int lane = tid & 63, w = tid >> 6;
  const int lr = lane & 15, lg = lane >> 4;

  // Q fragments in registers: rows q0+w*16+lr, k-chunks over d
  bf16x8 qf[4];
  {
    const u16* qp = Q + (size_t)(b * 2048 + q0 + w * 16 + lr) * HID + h * 128 + lg * 8;
#pragma unroll
    for (int kc = 0; kc < 4; kc++) qf[kc] = ld_bf8(qp + kc * 32);
  }

  float m[4], l[4];
  f32x4 o[8];
#pragma unroll
  for (int r = 0; r < 4; r++) { m[r] = -1e30f; l[r] = 0.f; }
#pragma unroll
  for (int d = 0; d < 8; d++) o[d] = 0.f;

  for (int kv0 = 0; kv0 < SEQ; kv0 += 64) {
    __syncthreads();
    // stage K tile [64][128] and VT tile [128][64]
#pragma unroll
    for (int i = 0; i < 4; i++) {
      int c = tid + i * 256;  // 0..1023
      int krow = c >> 4, kc8 = c & 15;  // 64 rows x 16 chunks
      u16x8v kvv = *(const u16x8v*)(K + (size_t)(b * 2048 + kv0 + krow) * HID + h * 128 + kc8 * 8);
      *(u16x8v*)&Ks[krow][kc8 * 8] = kvv;
      int drow = c >> 3, vc8 = c & 7;   // 128 rows x 8 chunks
      u16x8v vvv = *(const u16x8v*)(VT + (size_t)(h * 128 + drow) * MROWS + b * 2048 + kv0 + vc8 * 8);
      *(u16x8v*)&Vs[drow][vc8 * 8] = vvv;
    }
    __syncthreads();

    // S = Q K^T  (Q already scaled)
    f32x4 s[4];
#pragma unroll
    for (int nb = 0; nb < 4; nb++) {
      f32x4 a = {0.f, 0.f, 0.f, 0.f};
#pragma unroll
      for (int kc = 0; kc < 4; kc++) {
        bf16x8 kf = ld_bf8(&Ks[nb * 16 + lr][kc * 32 + lg * 8]);
        a = MFMA16(qf[kc], kf, a);
      }
      s[nb] = a;
    }

    // online softmax (per q-row r; row replicated across the 16 lanes lr)
#pragma unroll
    for (int r = 0; r < 4; r++) {
      float mx = fmaxf(fmaxf(s[0][r], s[1][r]), fmaxf(s[2][r], s[3][r]));
      mx = fmaxf(mx, __shfl_xor(mx, 1));
      mx = fmaxf(mx, __shfl_xor(mx, 2));
      mx = fmaxf(mx, __shfl_xor(mx, 4));
      mx = fmaxf(mx, __shfl_xor(mx, 8));
      float mn = fmaxf(m[r], mx);
      float sc = __expf(m[r] - mn);
      float ps = 0.f;
#pragma unroll
      for (int nb = 0; nb < 4; nb++) {
        float p = __expf(s[nb][r] - mn);
        s[nb][r] = p;
        ps += p;
      }
      ps += __shfl_xor(ps, 1);
      ps += __shfl_xor(ps, 2);
      ps += __shfl_xor(ps, 4);
      ps += __shfl_xor(ps, 8);
      l[r] = l[r] * sc + ps;
      m[r] = mn;
#pragma unroll
      for (int d = 0; d < 8; d++) o[d][r] *= sc;
    }

    // write P (bf16) to per-wave LDS, transposing D-layout -> A-layout
#pragma unroll
    for (int nb = 0; nb < 4; nb++)
#pragma unroll
      for (int r = 0; r < 4; r++)
        Ps[w][lg * 4 + r][nb * 16 + lr] = f2bf(s[nb][r]);
    __syncthreads();

    // O += P @ V
#pragma unroll
    for (int kc2 = 0; kc2 < 2; kc2++) {
      bf16x8 pf = ld_bf8(&Ps[w][lr][kc2 * 32 + lg * 8]);
#pragma unroll
      for (int d = 0; d < 8; d++) {
        bf16x8 vf = ld_bf8(&Vs[d * 16 + lr][kc2 * 32 + lg * 8]);
        o[d] = MFMA16(pf, vf, o[d]);
      }
    }
  }

  // epilogue: Ctx = O / l
#pragma unroll
  for (int d = 0; d < 8; d++) {
#pragma unroll
    for (int r = 0; r < 4; r++) {
      int row = b * 2048 + q0 + w * 16 + lg * 4 + r;
      int col = h * 128 + d * 16 + lr;
      Ctx[(size_t)row * HID + col] = f2bf(o[d][r] / l[r]);
    }
  }
}

extern "C" void kernel_launch(void* const* d_in, const int* in_sizes, int n_in,
                              void* d_out, int out_size, void* d_ws, size_t ws_size,
                              hipStream_t stream) {
  const float* X  = (const float*)d_in[0];
  const float* wq = (const float*)d_in[1];
  const float* bq = (const float*)d_in[2];
  const float* wk = (const float*)d_in[3];
  const float* bk = (const float*)d_in[4];
  const float* wv = (const float*)d_in[5];
  const float* bv = (const float*)d_in[6];
  const float* wo = (const float*)d_in[7];
  const float* bo = (const float*)d_in[8];
  float* out = (float*)d_out;

  const size_t M = 4096, H = 2048;
  u16* ws  = (u16*)d_ws;
  u16* Xb  = ws;                // [4096][2048]
  u16* WqT = Xb  + M * H;       // [2048][2048]
  u16* WkT = WqT + H * H;
  u16* WvT = WkT + H * H;
  u16* WoT = WvT + H * H;
  u16* Qb  = WoT + H * H;       // [4096][2048]
  u16* Kb  = Qb  + M * H;
  u16* Vb  = Kb  + M * H;
  u16* VbT = Vb  + M * H;       // [2048][4096]
  u16* Cx  = VbT + M * H;       // [4096][2048]

  dim3 tb(32, 8);

  cast_bf16<<<2048, 256, 0, stream>>>(X, Xb, (int)(M * H / 4));
  cast_transpose<<<dim3(64, 64), tb, 0, stream>>>(wq, WqT, 2048, 2048);
  cast_transpose<<<dim3(64, 64), tb, 0, stream>>>(wk, WkT, 2048, 2048);
  cast_transpose<<<dim3(64, 64), tb, 0, stream>>>(wv, WvT, 2048, 2048);
  cast_transpose<<<dim3(64, 64), tb, 0, stream>>>(wo, WoT, 2048, 2048);

  const float inv_sqrt_d = 0.08838834764831843f;  // 1/sqrt(128)
  gemm_bt<false><<<dim3(16, 32), 256, 0, stream>>>(Xb, WqT, bq, (void*)Qb, 4096, 2048, 2048, inv_sqrt_d);
  gemm_bt<false><<<dim3(16, 32), 256, 0, stream>>>(Xb, WkT, bk, (void*)Kb, 4096, 2048, 2048, 1.0f);
  gemm_bt<false><<<dim3(16, 32), 256, 0, stream>>>(Xb, WvT, bv, (void*)Vb, 4096, 2048, 2048, 1.0f);

  transpose_bf16<<<dim3(64, 128), tb, 0, stream>>>(Vb, VbT, 4096, 2048);

  attn_kernel<<<dim3(32, 32), 256, 0, stream>>>(Qb, Kb, VbT, Cx);

  gemm_bt<true><<<dim3(16, 32), 256, 0, stream>>>(Cx, WoT, bo, (void*)out, 4096, 2048, 2048, 1.0f);
}

// Round 2
// 467.091 us; speedup vs baseline: 1.2275x; 1.2275x over previous
//
#include <hip/hip_runtime.h>

typedef unsigned short u16;
typedef unsigned int u32;
typedef __bf16 bf16x8 __attribute__((ext_vector_type(8)));
typedef float f32x4 __attribute__((ext_vector_type(4)));
typedef float f32x16 __attribute__((ext_vector_type(16)));
typedef u16 u16x4v __attribute__((ext_vector_type(4)));
typedef u16 u16x8v __attribute__((ext_vector_type(8)));
typedef u32 u32x4v __attribute__((ext_vector_type(4)));

#define MFMA16(a, b, c) __builtin_amdgcn_mfma_f32_16x16x32_bf16((a), (b), (c), 0, 0, 0)
#define MFMA32(a, b, c) __builtin_amdgcn_mfma_f32_32x32x16_bf16((a), (b), (c), 0, 0, 0)

__device__ __forceinline__ u16 f2bf(float f) {
  union { float f; u32 u; } v; v.f = f;
  u32 r = v.u + 0x7fffu + ((v.u >> 16) & 1u);
  return (u16)(r >> 16);
}

__device__ __forceinline__ u32 packbf(float a, float b) {
  return (u32)f2bf(a) | ((u32)f2bf(b) << 16);
}

__device__ __forceinline__ bf16x8 ld_bf8(const u16* p) {
  u16x8v t = *(const u16x8v*)p;
  return __builtin_bit_cast(bf16x8, t);
}

// async global->LDS, 16B per lane, dest = wave-uniform base + lane*16
__device__ __forceinline__ void gl_lds16(const u16* g, u16* l) {
  __builtin_amdgcn_global_load_lds(
      (const __attribute__((address_space(1))) u32*)(const void*)g,
      (__attribute__((address_space(3))) u32*)(void*)l, 16, 0, 0);
}

// ---------------- cast fp32 -> bf16 (vectorized) ----------------
__global__ __launch_bounds__(256) void cast_bf16(const float* __restrict__ in,
                                                 u16* __restrict__ out, int n4) {
  int idx = blockIdx.x * 256 + threadIdx.x;
  int stride = gridDim.x * 256;
  for (int i = idx; i < n4; i += stride) {
    float4 v = ((const float4*)in)[i];
    u16x4v o = {f2bf(v.x), f2bf(v.y), f2bf(v.z), f2bf(v.w)};
    *(u16x4v*)(out + (size_t)i * 4) = o;
  }
}

// ---------------- cast+transpose fp32 W[R][C] -> bf16 WT[C][R] ----------------
__global__ __launch_bounds__(256) void cast_transpose(const float* __restrict__ W,
                                                      u16* __restrict__ WT, int R, int C) {
  __shared__ float t[32][33];
  int bx = blockIdx.x * 32, by = blockIdx.y * 32;
  int tx = threadIdx.x, ty = threadIdx.y;  // (32,8)
#pragma unroll
  for (int i = 0; i < 4; i++)
    t[ty + i * 8][tx] = W[(size_t)(by + ty + i * 8) * C + bx + tx];
  __syncthreads();
#pragma unroll
  for (int i = 0; i < 4; i++)
    WT[(size_t)(bx + ty + i * 8) * R + by + tx] = f2bf(t[tx][ty + i * 8]);
}

// ---------------- transpose bf16 V[R][C] -> VT[C][R] ----------------
__global__ __launch_bounds__(256) void transpose_bf16(const u16* __restrict__ V,
                                                      u16* __restrict__ VT, int R, int C) {
  __shared__ u16 t[32][33];
  int bx = blockIdx.x * 32, by = blockIdx.y * 32;
  int tx = threadIdx.x, ty = threadIdx.y;
#pragma unroll
  for (int i = 0; i < 4; i++)
    t[ty + i * 8][tx] = V[(size_t)(by + ty + i * 8) * C + bx + tx];
  __syncthreads();
#pragma unroll
  for (int i = 0; i < 4; i++)
    VT[(size_t)(bx + ty + i * 8) * R + by + tx] = t[tx][ty + i * 8];
}

// ---------------- GEMM: C[M][N] = alpha*(A[M][K] @ BT[N][K]^T + bias[N]) ----------------
// 128x128 tile, BK=64, 4 waves 2x2, m97-style global_load_lds staging.
template <bool OUT_F32>
__global__ __launch_bounds__(256) void gemm_bt(const u16* __restrict__ A,
                                               const u16* __restrict__ BT,
                                               const float* __restrict__ bias,
                                               void* __restrict__ Cout,
                                               int M, int N, int K, float alpha) {
  __shared__ u16 As[128][64];
  __shared__ u16 Bs[128][64];
  const int tid = threadIdx.x;
  const int lane = tid & 63, wid = tid >> 6;
  const int wm = wid >> 1, wn = wid & 1;
  const int bm0 = blockIdx.y * 128, bn0 = blockIdx.x * 128;
  const int lr = lane & 15, lg = lane >> 4;

  // staging geometry: wave w owns rows [w*32, w*32+32); 1 issue = 8 rows
  const int srow = lane >> 3;             // 0..7
  const int scol = (lane & 7) * 8;        // u16 col, 16B chunks
  const u16* aw = A + (size_t)(bm0 + wid * 32) * K;
  const u16* bw = BT + (size_t)(bn0 + wid * 32) * K;

  f32x4 acc[4][4] = {};

  for (int k0 = 0; k0 < K; k0 += 64) {
    __syncthreads();
#pragma unroll
    for (int i = 0; i < 4; i++) {
      gl_lds16(aw + (size_t)(i * 8 + srow) * K + k0 + scol, &As[wid * 32 + i * 8][0]);
      gl_lds16(bw + (size_t)(i * 8 + srow) * K + k0 + scol, &Bs[wid * 32 + i * 8][0]);
    }
    __syncthreads();
#pragma unroll
    for (int kk = 0; kk < 2; kk++) {
      bf16x8 af[4], bfr[4];
#pragma unroll
      for (int i = 0; i < 4; i++)
        af[i] = ld_bf8(&As[wm * 64 + i * 16 + lr][kk * 32 + lg * 8]);
#pragma unroll
      for (int j = 0; j < 4; j++)
        bfr[j] = ld_bf8(&Bs[wn * 64 + j * 16 + lr][kk * 32 + lg * 8]);
#pragma unroll
      for (int i = 0; i < 4; i++)
#pragma unroll
        for (int j = 0; j < 4; j++)
          acc[i][j] = MFMA16(af[i], bfr[j], acc[i][j]);
    }
  }

#pragma unroll
  for (int i = 0; i < 4; i++) {
#pragma unroll
    for (int j = 0; j < 4; j++) {
      int col = bn0 + wn * 64 + j * 16 + lr;
      float bv = bias[col];
#pragma unroll
      for (int r = 0; r < 4; r++) {
        int row = bm0 + wm * 64 + i * 16 + lg * 4 + r;
        float v = alpha * (acc[i][j][r] + bv);
        if (OUT_F32)
          ((float*)Cout)[(size_t)row * N + col] = v;
        else
          ((u16*)Cout)[(size_t)row * N + col] = f2bf(v);
      }
    }
  }
}

// ---------------- Flash attention, 32x32 MFMA, swapped operands, no LDS ----------------
// Q,K: [4096][2048] bf16 (row = b*2048+s, col = h*128+d), Q pre-scaled by 1/sqrt(D)
// VT:  [2048][4096] bf16 (row = h*128+d, col = b*2048+s)
// Ctx: [4096][2048] bf16
// Block: 256 thr = 4 waves; wave w handles q-rows [blockIdx.x*128 + w*32, +32).
// Per wave: lane owns q = q0 + (lane&31). S^T = mfma(Kfrag, Qfrag): D col = own q,
// D row = kv = (r&3)+8*(r>>2)+4*hi. O^T = mfma(VTfrag, Pfrag): D col = own q,
// D row = d. Softmax entirely per-lane + one shfl_xor(32).
__global__ __launch_bounds__(256) void attn32(const u16* __restrict__ Q,
                                              const u16* __restrict__ K,
                                              const u16* __restrict__ VT,
                                              u16* __restrict__ Ctx) {
  const int HID = 2048, SEQ = 2048, MT = 4096;
  const int tid = threadIdx.x;
  const int lane = tid & 63, w = tid >> 6;
  const int ql = lane & 31, hi = lane >> 5;
  const int bh = blockIdx.y, b = bh >> 4, h = bh & 15;
  const int q0 = blockIdx.x * 128 + w * 32;

  // Q fragments (B-operand): lane holds Q[q0+ql][d = c*16 + hi*8 + j]
  bf16x8 qf[8];
  {
    const u16* qp = Q + (size_t)(b * 2048 + q0 + ql) * HID + h * 128 + hi * 8;
#pragma unroll
    for (int c = 0; c < 8; c++) qf[c] = ld_bf8(qp + c * 16);
  }

  f32x16 o[4] = {};
  float m = -1e30f, l = 0.f;

  const u16* kbase = K + (size_t)(b * 2048 + ql) * HID + h * 128 + hi * 8;
  const u16* vbase = VT + (size_t)(h * 128 + ql) * MT + b * 2048 + hi * 8;

  for (int kv0 = 0; kv0 < SEQ; kv0 += 32) {
    // S^T[kv][q] over this 32-kv block
    f32x16 s = {};
    const u16* kp = kbase + (size_t)kv0 * HID;
#pragma unroll
    for (int c = 0; c < 8; c++) s = MFMA32(ld_bf8(kp + c * 16), qf[c], s);

    // per-lane max over own q's 16 kv values, + partner half
    float pmax = s[0];
#pragma unroll
    for (int r = 1; r < 16; r++) pmax = fmaxf(pmax, s[r]);
    float pm = fmaxf(pmax, __shfl_xor(pmax, 32));

    // defer-max (T13): only rescale when max grew past threshold
    if (__any(pm > m + 8.f)) {
      float mn = fmaxf(m, pm);
      float sc = __expf(m - mn);
      l *= sc;
      m = mn;
#pragma unroll
      for (int d = 0; d < 4; d++)
#pragma unroll
        for (int r = 0; r < 16; r++) o[d][r] *= sc;
    }

    float p[16], ps = 0.f;
#pragma unroll
    for (int r = 0; r < 16; r++) {
      p[r] = __expf(s[r] - m);
      ps += p[r];
    }
    ps += __shfl_xor(ps, 32);
    l += ps;

    // pack to bf16 pairs: regs 4T..4T+3 hold kv = 8T + 4*hi + {0..3}
    u32 p2[8];
#pragma unroll
    for (int T = 0; T < 4; T++) {
      p2[2 * T] = packbf(p[4 * T], p[4 * T + 1]);
      p2[2 * T + 1] = packbf(p[4 * T + 2], p[4 * T + 3]);
    }
    u32 x2[8];
#pragma unroll
    for (int j = 0; j < 8; j++) x2[j] = __shfl_xor(p2[j], 32);

    // build B-frags: lane needs P[own q][kv = c*16 + hi*8 + j]
    bf16x8 pf[2];
    {
      u32x4v f0 = {hi ? x2[2] : p2[0], hi ? x2[3] : p2[1],
                   hi ? p2[2] : x2[0], hi ? p2[3] : x2[1]};
      pf[0] = __builtin_bit_cast(bf16x8, f0);
      u32x4v f1 = {hi ? x2[6] : p2[4], hi ? x2[7] : p2[5],
                   hi ? p2[6] : x2[4], hi ? p2[7] : x2[5]};
      pf[1] = __builtin_bit_cast(bf16x8, f1);
    }

    // O^T += V^T-frag x P-frag
    const u16* vp = vbase + kv0;
#pragma unroll
    for (int dblk = 0; dblk < 4; dblk++) {
#pragma unroll
      for (int c = 0; c < 2; c++)
        o[dblk] = MFMA32(ld_bf8(vp + (size_t)dblk * 32 * MT + c * 16), pf[c], o[dblk]);
    }
  }

  // epilogue: lane's column is its own q; normalize by own l
  float rn = 1.f / l;
  u16* cp = Ctx + (size_t)(b * 2048 + q0 + ql) * HID + h * 128;
#pragma unroll
  for (int dblk = 0; dblk < 4; dblk++) {
#pragma unroll
    for (int g = 0; g < 4; g++) {
      u16x4v ov = {f2bf(o[dblk][4 * g] * rn), f2bf(o[dblk][4 * g + 1] * rn),
                   f2bf(o[dblk][4 * g + 2] * rn), f2bf(o[dblk][4 * g + 3] * rn)};
      *(u16x4v*)(cp + dblk * 32 + g * 8 + hi * 4) = ov;
    }
  }
}

extern "C" void kernel_launch(void* const* d_in, const int* in_sizes, int n_in,
                              void* d_out, int out_size, void* d_ws, size_t ws_size,
                              hipStream_t stream) {
  const float* X  = (const float*)d_in[0];
  const float* wq = (const float*)d_in[1];
  const float* bq = (const float*)d_in[2];
  const float* wk = (const float*)d_in[3];
  const float* bk = (const float*)d_in[4];
  const float* wv = (const float*)d_in[5];
  const float* bv = (const float*)d_in[6];
  const float* wo = (const float*)d_in[7];
  const float* bo = (const float*)d_in[8];
  float* out = (float*)d_out;

  const size_t M = 4096, H = 2048;
  u16* ws  = (u16*)d_ws;
  u16* Xb  = ws;                // [4096][2048]
  u16* WqT = Xb  + M * H;       // [2048][2048]
  u16* WkT = WqT + H * H;
  u16* WvT = WkT + H * H;
  u16* WoT = WvT + H * H;
  u16* Qb  = WoT + H * H;       // [4096][2048]
  u16* Kb  = Qb  + M * H;
  u16* Vb  = Kb  + M * H;
  u16* VbT = Vb  + M * H;       // [2048][4096]
  u16* Cx  = VbT + M * H;       // [4096][2048]

  dim3 tb(32, 8);

  cast_bf16<<<2048, 256, 0, stream>>>(X, Xb, (int)(M * H / 4));
  cast_transpose<<<dim3(64, 64), tb, 0, stream>>>(wq, WqT, 2048, 2048);
  cast_transpose<<<dim3(64, 64), tb, 0, stream>>>(wk, WkT, 2048, 2048);
  cast_transpose<<<dim3(64, 64), tb, 0, stream>>>(wv, WvT, 2048, 2048);
  cast_transpose<<<dim3(64, 64), tb, 0, stream>>>(wo, WoT, 2048, 2048);

  const float inv_sqrt_d = 0.08838834764831843f;  // 1/sqrt(128)
  gemm_bt<false><<<dim3(16, 32), 256, 0, stream>>>(Xb, WqT, bq, (void*)Qb, 4096, 2048, 2048, inv_sqrt_d);
  gemm_bt<false><<<dim3(16, 32), 256, 0, stream>>>(Xb, WkT, bk, (void*)Kb, 4096, 2048, 2048, 1.0f);
  gemm_bt<false><<<dim3(16, 32), 256, 0, stream>>>(Xb, WvT, bv, (void*)Vb, 4096, 2048, 2048, 1.0f);

  transpose_bf16<<<dim3(64, 128), tb, 0, stream>>>(Vb, VbT, 4096, 2048);

  attn32<<<dim3(16, 32), 256, 0, stream>>>(Qb, Kb, VbT, Cx);

  gemm_bt<true><<<dim3(16, 32), 256, 0, stream>>>(Cx, WoT, bo, (void*)out, 4096, 2048, 2048, 1.0f);
}